// Round 7
// baseline (213.238 us; speedup 1.0000x reference)
//
#include <hip/hip_runtime.h>

#define NB 32768
#define NCH 8
#define ROWS 32  // rows per block -> 1024 blocks, 4 waves each, no LDS, no barriers

typedef __bf16 bf16x8 __attribute__((ext_vector_type(8)));
typedef float f32x4 __attribute__((ext_vector_type(4)));
typedef float f32x16 __attribute__((ext_vector_type(16)));
typedef unsigned int u32;
typedef unsigned short u16;
typedef u32 u32x4v __attribute__((ext_vector_type(4)));

// bf16 weights, transposed to [n][k]. Order: 0=Wi 1=Wf 2=Wo 3=Wu 4=Ui 5=Uf 6=Uo 7=Uu
__device__ __align__(16) u16 g_wt[8 * 128 * 128];

__device__ __forceinline__ u16 f2bf(float f) {
  u32 u = __builtin_bit_cast(u32, f);
  u32 r = u + 0x7FFFu + ((u >> 16) & 1u);  // RNE
  return (u16)(r >> 16);
}
__device__ __forceinline__ float sigm(float s) {
  return __builtin_amdgcn_rcpf(1.0f + __expf(-s));
}
__device__ __forceinline__ float tanh_f(float v) {
  float e = __expf(2.0f * v);
  return 1.0f - 2.0f * __builtin_amdgcn_rcpf(e + 1.0f);
}

__global__ void prep_weights(const float* __restrict__ Wi, const float* __restrict__ Wf,
                             const float* __restrict__ Wo, const float* __restrict__ Wu,
                             const float* __restrict__ Ui, const float* __restrict__ Uf,
                             const float* __restrict__ Uo, const float* __restrict__ Uu) {
  __shared__ float t[128][129];
  const float* srcs[8] = {Wi, Wf, Wo, Wu, Ui, Uf, Uo, Uu};
  const float* s = srcs[blockIdx.x];
  for (int i = threadIdx.x; i < 16384; i += 256) t[i >> 7][i & 127] = s[i];
  __syncthreads();
  u16* dst = g_wt + blockIdx.x * 16384;
  for (int i = threadIdx.x; i < 16384; i += 256) {
    int n = i >> 7, k = i & 127;
    dst[i] = f2bf(t[k][n]);
  }
}

__device__ __forceinline__ bf16x8 cvt8(f32x4 lo, f32x4 hi) {
  bf16x8 r;
  r[0] = (__bf16)lo[0]; r[1] = (__bf16)lo[1]; r[2] = (__bf16)lo[2]; r[3] = (__bf16)lo[3];
  r[4] = (__bf16)hi[0]; r[5] = (__bf16)hi[1]; r[6] = (__bf16)hi[2]; r[7] = (__bf16)hi[3];
  return r;
}

// B-fragment for 32x32x16: col = lane&31, k = ks*16 + (lane>>5)*8 + e.
// g_wt is [col][k] so this is one contiguous 16B load.
__device__ __forceinline__ bf16x8 ldB32(const u16* wt, int col, int ks, int hi) {
  return __builtin_bit_cast(bf16x8,
      *(const u32x4v*)(wt + col * 128 + ks * 16 + hi * 8));
}

// A-fragment for 32x32x16 from a global f32 row: row = lane&31, k = ks*16 + hi*8 + e.
__device__ __forceinline__ bf16x8 ldA32(const float* __restrict__ rowp, int ks, int hi) {
  f32x4 lo = *(const f32x4*)(rowp + ks * 16 + hi * 8);
  f32x4 hg = *(const f32x4*)(rowp + ks * 16 + hi * 8 + 4);
  return cvt8(lo, hg);
}

#define MFMA32(A, B, ACC) __builtin_amdgcn_mfma_f32_32x32x16_bf16((A), (B), (ACC), 0, 0, 0)

__global__ __launch_bounds__(256) void tree_lstm(
    const float* __restrict__ x, const float* __restrict__ h, const float* __restrict__ C,
    const float* __restrict__ b_i, const float* __restrict__ b_f,
    const float* __restrict__ b_o, const float* __restrict__ b_u,
    float* __restrict__ out) {
  const int tid = threadIdx.x;
  const int lane = tid & 63;
  const int wv = tid >> 6;
  const int row0 = blockIdx.x * ROWS;
  const int arow = lane & 31;         // A-operand row within tile
  const int hi = lane >> 5;           // k half (0/1)
  const int col = wv * 32 + (lane & 31);  // B col == C/D col (wave owns 32 cols)
  const int crb = 4 * hi;             // C/D row adjustment

  const f32x16 z = {0.f, 0.f, 0.f, 0.f, 0.f, 0.f, 0.f, 0.f,
                    0.f, 0.f, 0.f, 0.f, 0.f, 0.f, 0.f, 0.f};

  const float* xrow = x + (size_t)(row0 + arow) * 128;
  const u16* Wi = g_wt + 0 * 16384;
  const u16* Wf = g_wt + 1 * 16384;
  const u16* Wo = g_wt + 2 * 16384;
  const u16* Wu = g_wt + 3 * 16384;
  const u16* Ui = g_wt + 4 * 16384;
  const u16* Uf = g_wt + 5 * 16384;
  const u16* Uo = g_wt + 6 * 16384;
  const u16* Uu = g_wt + 7 * 16384;

  const float bfv = b_f[col], biv = b_i[col], bov = b_o[col], buv = b_u[col];

  // afx = x @ Wf (fragment layout, this wave's 32x32 slice)
  f32x16 afx = z;
#pragma unroll
  for (int ks = 0; ks < 8; ++ks) {
    bf16x8 xa = ldA32(xrow, ks, hi);
    afx = MFMA32(xa, ldB32(Wf, col, ks, hi), afx);
  }

  f32x16 iacc = z, oacc = z, uacc = z, fca = z;

  // ---- child loop: no LDS, no barriers; i/o/u accumulate across children ----
  for (int n = 0; n < NCH; ++n) {
    const float* hrow = h + ((size_t)n * NB + row0 + arow) * 128;
    const float* Cn = C + ((size_t)n * NB + row0) * 128;

    // C fragment loads (full 128B lines per instruction) issued early
    f32x16 cf;
#pragma unroll
    for (int r = 0; r < 16; ++r)
      cf[r] = Cn[(size_t)((r & 3) + 8 * (r >> 2) + crb) * 128 + col];

    f32x16 facc = z;
#pragma unroll
    for (int ks = 0; ks < 8; ++ks) {
      bf16x8 ha = ldA32(hrow, ks, hi);
      facc = MFMA32(ha, ldB32(Uf, col, ks, hi), facc);
      iacc = MFMA32(ha, ldB32(Ui, col, ks, hi), iacc);
      oacc = MFMA32(ha, ldB32(Uo, col, ks, hi), oacc);
      uacc = MFMA32(ha, ldB32(Uu, col, ks, hi), uacc);
    }

    // fused f-gate epilogue: fca += sigmoid(f + afx + b_f) * C[n]
#pragma unroll
    for (int r = 0; r < 16; ++r)
      fca[r] += sigm(facc[r] + afx[r] + bfv) * cf[r];
  }

  // ---- x contributions to i/o/u (x row is L1/L2-hot) ----
#pragma unroll
  for (int ks = 0; ks < 8; ++ks) {
    bf16x8 xa = ldA32(xrow, ks, hi);
    iacc = MFMA32(xa, ldB32(Wi, col, ks, hi), iacc);
    oacc = MFMA32(xa, ldB32(Wo, col, ks, hi), oacc);
    uacc = MFMA32(xa, ldB32(Wu, col, ks, hi), uacc);
  }

  // ---- outputs: full-line coalesced stores in fragment layout ----
  float* outc = out + (size_t)NB * 128;
#pragma unroll
  for (int r = 0; r < 16; ++r) {
    int row = row0 + (r & 3) + 8 * (r >> 2) + crb;
    float iv = sigm(iacc[r] + biv);
    float uv = tanh_f(uacc[r] + buv);
    float cv = iv * uv + fca[r];
    outc[(size_t)row * 128 + col] = cv;
    out[(size_t)row * 128 + col] = sigm(oacc[r] + bov) * tanh_f(cv);
  }
}

extern "C" void kernel_launch(void* const* d_in, const int* in_sizes, int n_in,
                              void* d_out, int out_size, void* d_ws, size_t ws_size,
                              hipStream_t stream) {
  (void)in_sizes; (void)n_in; (void)out_size; (void)d_ws; (void)ws_size;
  const float* x = (const float*)d_in[0];
  const float* h = (const float*)d_in[1];
  const float* C = (const float*)d_in[2];

  prep_weights<<<8, 256, 0, stream>>>(
      (const float*)d_in[3], (const float*)d_in[4], (const float*)d_in[5],
      (const float*)d_in[6], (const float*)d_in[7], (const float*)d_in[8],
      (const float*)d_in[9], (const float*)d_in[10]);

  tree_lstm<<<NB / ROWS, 256, 0, stream>>>(
      x, h, C,
      (const float*)d_in[11], (const float*)d_in[12],
      (const float*)d_in[13], (const float*)d_in[14],
      (float*)d_out);
}